// Round 1
// baseline (1076.969 us; speedup 1.0000x reference)
//
#include <hip/hip_runtime.h>

// ChebNet classifier: 3x ChebConv(K=6) + 2x sparse pool + linear head.
// All f32. Correctness-first round; fusion/optimization in later rounds.

#define TPB 256

static inline int gs(long long n) { return (int)((n + TPB - 1) / TPB); }

__global__ void k_deg(const int* __restrict__ row, float* __restrict__ deg, int E) {
    int e = blockIdx.x * blockDim.x + threadIdx.x;
    if (e < E) atomicAdd(&deg[row[e]], 1.0f);
}

__global__ void k_dinv(float* __restrict__ deg, int n) {
    int i = blockIdx.x * blockDim.x + threadIdx.x;
    if (i < n) {
        float d = deg[i];
        deg[i] = d > 0.f ? 1.0f / sqrtf(d) : 0.f;
    }
}

__global__ void k_w(const int* __restrict__ row, const int* __restrict__ col,
                    const float* __restrict__ dinv, float* __restrict__ w, int E) {
    int e = blockIdx.x * blockDim.x + threadIdx.x;
    if (e < E) w[e] = -dinv[row[e]] * dinv[col[e]];
}

__global__ void k_neg(float* __restrict__ dst, const float* __restrict__ src, int n) {
    int i = blockIdx.x * blockDim.x + threadIdx.x;
    if (i < n) dst[i] = -src[i];
}

// dst[row[e]*C + c] += scale * w[e] * src[col[e]*C + c]
__global__ void k_prop(const int* __restrict__ row, const int* __restrict__ col,
                       const float* __restrict__ w, const float* __restrict__ src,
                       float* __restrict__ dst, int E, int C, float scale) {
    int idx = blockIdx.x * blockDim.x + threadIdx.x;
    if (idx >= E * C) return;
    int e = idx / C, c = idx - e * C;
    atomicAdd(&dst[row[e] * C + c], scale * w[e] * src[col[e] * C + c]);
}

// out[n][co] (+)= sum_ci tx[n][ci] * W[ci][co]   (init: start from b[co])
__global__ void k_addmm(float* __restrict__ out, const float* __restrict__ tx,
                        const float* __restrict__ W, const float* __restrict__ b,
                        int n, int Cin, int Cout, int init) {
    int idx = blockIdx.x * blockDim.x + threadIdx.x;
    if (idx >= n * Cout) return;
    int node = idx / Cout, co = idx - node * Cout;
    const float* xr = tx + (long long)node * Cin;
    float acc = init ? b[co] : out[idx];
    for (int ci = 0; ci < Cin; ++ci) acc += xr[ci] * W[ci * Cout + co];
    out[idx] = acc;
}

// out[rows[i]][c] += vals[i] * relu?(x[cols[i]][c])
__global__ void k_pool(const int* __restrict__ rows, const int* __restrict__ cols,
                       const float* __restrict__ vals, const float* __restrict__ x,
                       float* __restrict__ out, int nnz, int C, int relu) {
    int idx = blockIdx.x * blockDim.x + threadIdx.x;
    if (idx >= nnz * C) return;
    int i = idx / C, c = idx - i * C;
    float v = x[cols[i] * C + c];
    if (relu) v = fmaxf(v, 0.f);
    atomicAdd(&out[rows[i] * C + c], vals[i] * v);
}

__global__ void k_init_out(float* __restrict__ out, const float* __restrict__ b, int n) {
    int i = blockIdx.x * blockDim.x + threadIdx.x;
    if (i < n) out[i] = b[i];
}

// Z[j] += sum_i lw[j*len + i] * x[i] ; per-wave shuffle reduce then atomicAdd
__global__ void k_linear(const float* __restrict__ lw, const float* __restrict__ x,
                         float* __restrict__ out, int len) {
    float acc[10];
#pragma unroll
    for (int j = 0; j < 10; ++j) acc[j] = 0.f;
    for (int i = blockIdx.x * blockDim.x + threadIdx.x; i < len;
         i += gridDim.x * blockDim.x) {
        float xv = x[i];
#pragma unroll
        for (int j = 0; j < 10; ++j) acc[j] += lw[j * len + i] * xv;
    }
#pragma unroll
    for (int j = 0; j < 10; ++j) {
        float v = acc[j];
        for (int off = 32; off > 0; off >>= 1) v += __shfl_down(v, off, 64);
        if ((threadIdx.x & 63) == 0) atomicAdd(&out[j], v);
    }
}

extern "C" void kernel_launch(void* const* d_in, const int* in_sizes, int n_in,
                              void* d_out, int out_size, void* d_ws, size_t ws_size,
                              hipStream_t stream) {
    const int cN0 = 100000, cN1 = 25000, cN2 = 6250;
    const int cE0 = 600000, cE1 = 150000, cE2 = 40000;

    const float* pos = (const float*)d_in[0];
    const int*   ei0 = (const int*)d_in[1];
    const int*   ei1 = (const int*)d_in[2];
    const int*   ei2 = (const int*)d_in[3];
    const int*   d0r = (const int*)d_in[4];
    const int*   d0c = (const int*)d_in[5];
    const float* d0v = (const float*)d_in[6];
    const int*   d1r = (const int*)d_in[7];
    const int*   d1c = (const int*)d_in[8];
    const float* d1v = (const float*)d_in[9];
    const float* W0  = (const float*)d_in[10];
    const float* b0  = (const float*)d_in[11];
    const float* W1  = (const float*)d_in[12];
    const float* b1  = (const float*)d_in[13];
    const float* W2  = (const float*)d_in[14];
    const float* b2  = (const float*)d_in[15];
    const float* lw  = (const float*)d_in[16];
    const float* lb  = (const float*)d_in[17];
    float* outZ = (float*)d_out;

    // workspace layout (floats): 28.4 MB total
    float* ws      = (float*)d_ws;
    float* deg     = ws;                   // 100000
    float* wed     = deg + 100000;         // 600000
    float* txA     = wed + 600000;         // 800000 (>= max n*Cin = N1*32)
    float* txB     = txA + 800000;         // 800000
    float* txC     = txB + 800000;         // 800000
    float* bufOut  = txC + 800000;         // 3200000 (>= N0*32)
    float* bufPool = bufOut + 3200000;     // 800000  (>= N1*32)

    auto conv = [&](const float* x, const int* ei, int E, int n, int Cin, int Cout,
                    const float* W, const float* b, float* out) {
        // edge weights: w = -dinv[row]*dinv[col], deg over row
        hipMemsetAsync(deg, 0, (size_t)n * sizeof(float), stream);
        k_deg<<<gs(E), TPB, 0, stream>>>(ei, deg, E);
        k_dinv<<<gs(n), TPB, 0, stream>>>(deg, n);
        k_w<<<gs(E), TPB, 0, stream>>>(ei, ei + E, deg, wed, E);

        // k = 0: out = b + x @ W[0]
        k_addmm<<<gs((long long)n * Cout), TPB, 0, stream>>>(out, x, W, b, n, Cin, Cout, 1);

        // k = 1: Tx1 = prop(x); out += Tx1 @ W[1]
        float* bufs[3] = {txA, txB, txC};
        const float* tx0 = x;
        float* tx1 = txA;
        hipMemsetAsync(tx1, 0, (size_t)n * Cin * sizeof(float), stream);
        k_prop<<<gs((long long)E * Cin), TPB, 0, stream>>>(ei, ei + E, wed, x, tx1, E, Cin, 1.0f);
        k_addmm<<<gs((long long)n * Cout), TPB, 0, stream>>>(out, tx1, W + 1 * Cin * Cout, b, n, Cin, Cout, 0);

        // k = 2..5: Tx2 = 2*prop(Tx1) - Tx0 (init Tx2 = -Tx0, scatter 2*w*Tx1)
        int nxt = 1;
        for (int k = 2; k < 6; ++k) {
            float* tx2 = bufs[nxt];
            k_neg<<<gs((long long)n * Cin), TPB, 0, stream>>>(tx2, tx0, n * Cin);
            k_prop<<<gs((long long)E * Cin), TPB, 0, stream>>>(ei, ei + E, wed, tx1, tx2, E, Cin, 2.0f);
            k_addmm<<<gs((long long)n * Cout), TPB, 0, stream>>>(out, tx2, W + k * Cin * Cout, b, n, Cin, Cout, 0);
            tx0 = tx1; tx1 = tx2; nxt = (nxt + 1) % 3;
        }
    };

    // layer 0: pos (N0x3) -> bufOut (N0x32); relu folded into pool gather
    conv(pos, ei0, cE0, cN0, 3, 32, W0, b0, bufOut);
    hipMemsetAsync(bufPool, 0, (size_t)cN1 * 32 * sizeof(float), stream);
    k_pool<<<gs((long long)cN0 * 32), TPB, 0, stream>>>(d0r, d0c, d0v, bufOut, bufPool, cN0, 32, 1);

    // layer 1: bufPool (N1x32) -> bufOut (N1x64)
    conv(bufPool, ei1, cE1, cN1, 32, 64, W1, b1, bufOut);
    hipMemsetAsync(bufPool, 0, (size_t)cN2 * 64 * sizeof(float), stream);
    k_pool<<<gs((long long)cN1 * 64), TPB, 0, stream>>>(d1r, d1c, d1v, bufOut, bufPool, cN1, 64, 1);

    // layer 2: bufPool (N2x64) -> bufOut (N2x128), no relu
    conv(bufPool, ei2, cE2, cN2, 64, 128, W2, b2, bufOut);

    // linear head: Z = lin_w @ flat(bufOut) + lin_b
    k_init_out<<<1, 64, 0, stream>>>(outZ, lb, 10);
    k_linear<<<512, TPB, 0, stream>>>(lw, bufOut, outZ, cN2 * 128);
}